// Round 20
// baseline (118.689 us; speedup 1.0000x reference)
//
#include <hip/hip_runtime.h>

#define NHEADS 16
#define SEQ    2048
#define BATCH  2
#define DMODEL 1024
#define MTOT   4096   // BATCH*SEQ

typedef __attribute__((ext_vector_type(8)))  short short8;
typedef __attribute__((ext_vector_type(4)))  float f32x4;
typedef __attribute__((ext_vector_type(16))) float f32x16;

__device__ __forceinline__ unsigned short f32_to_bf16_rn(float x) {
  unsigned int u = __float_as_uint(x);
  u += 0x7fffu + ((u >> 16) & 1u);   // RNE
  return (unsigned short)(u >> 16);
}

__device__ __forceinline__ unsigned cvt_pk_bf16(float lo, float hi_) {
  unsigned r;
  asm("v_cvt_pk_bf16_f32 %0, %1, %2" : "=v"(r) : "v"(lo), "v"(hi_));
  return r;
}

// v_permlane32_swap_b32: after: a = {a.lo, b.lo}, b = {a.hi, b.hi}
__device__ __forceinline__ void permlane32_swap(unsigned &a, unsigned &b) {
  asm("v_permlane32_swap_b32 %0, %1" : "+v"(a), "+v"(b));
}

__device__ __forceinline__ void async16(void* lds, const void* g) {
  __builtin_amdgcn_global_load_lds((const __attribute__((address_space(1))) unsigned int*)g,
                                   (__attribute__((address_space(3))) unsigned int*)lds, 16, 0, 0);
}

// ---------------- fp32 -> bf16 conversion prepass: WEIGHTS ONLY (X fused into qkv) ----------
__global__ void cvt_w_kernel(const float* __restrict__ w0, const float* __restrict__ w1,
                             const float* __restrict__ w2, const float* __restrict__ w3,
                             unsigned short* __restrict__ obase)
{
  const int which = blockIdx.y;
  const float* src = which==0 ? w0 : which==1 ? w1 : which==2 ? w2 : w3;
  const int i = (blockIdx.x*256 + threadIdx.x)*8;
  const float4 v0 = *(const float4*)(src + i);
  const float4 v1 = *(const float4*)(src + i + 4);
  union { unsigned short u[8]; uint4 v; } r;
  r.u[0] = f32_to_bf16_rn(v0.x); r.u[1] = f32_to_bf16_rn(v0.y);
  r.u[2] = f32_to_bf16_rn(v0.z); r.u[3] = f32_to_bf16_rn(v0.w);
  r.u[4] = f32_to_bf16_rn(v1.x); r.u[5] = f32_to_bf16_rn(v1.y);
  r.u[6] = f32_to_bf16_rn(v1.z); r.u[7] = f32_to_bf16_rn(v1.w);
  *(uint4*)(obase + (size_t)which*1048576 + i) = r.v;
}

// ---------------- shared NT-GEMM core (bf16 A) — used by oproj ----------------
template<int BM>
__device__ __forceinline__ void gemm_core(const unsigned short* __restrict__ A,
                                          const unsigned short* __restrict__ W,
                                          unsigned short* sA, unsigned short* sB,
                                          int m0, int n0, f32x4 (&acc)[BM/32][4])
{
  constexpr int MI = BM/32;
  const int t = threadIdx.x;
  const int lane = t & 63;
  const int wv = t >> 6;
  const int wm = wv >> 1, wn = wv & 1;
  const int lr = lane & 15, lk = lane >> 4;

  for (int kt = 0; kt < DMODEL/64; ++kt) {
    #pragma unroll
    for (int g = 0; g < MI; ++g) {
      const int o  = g*4096 + t*16;
      const int so = o ^ (((o >> 7) & 7) << 4);
      const int row = so >> 7, colE = (so & 127) >> 1;
      async16((char*)sA + o, A + (size_t)(m0 + row)*DMODEL + kt*64 + colE);
    }
    #pragma unroll
    for (int g = 0; g < 4; ++g) {
      const int o  = g*4096 + t*16;
      const int so = o ^ (((o >> 7) & 7) << 4);
      const int row = so >> 7, colE = (so & 127) >> 1;
      async16((char*)sB + o, W + (size_t)(n0 + row)*DMODEL + kt*64 + colE);
    }
    __syncthreads();
    #pragma unroll
    for (int ks = 0; ks < 2; ++ks) {
      short8 af[MI], bf[4];
      #pragma unroll
      for (int mi = 0; mi < MI; ++mi) {
        const int row = wm*(BM/2) + mi*16 + lr;
        const int sl  = (ks*4 + lk) ^ (row & 7);
        af[mi] = *(const short8*)(sA + row*64 + sl*8);
      }
      #pragma unroll
      for (int ni = 0; ni < 4; ++ni) {
        const int row = wn*64 + ni*16 + lr;
        const int sl  = (ks*4 + lk) ^ (row & 7);
        bf[ni] = *(const short8*)(sB + row*64 + sl*8);
      }
      #pragma unroll
      for (int mi = 0; mi < MI; ++mi)
        #pragma unroll
        for (int ni = 0; ni < 4; ++ni)
          acc[mi][ni] = __builtin_amdgcn_mfma_f32_16x16x32_bf16(af[mi], bf[ni], acc[mi][ni], 0, 0, 0);
    }
    __syncthreads();
  }
}

// ---------------- fused QKV projection: R11 loop skeleton, BM=256 x BN=128, 512 threads ----
// grid (16, 24) = 384 blocks at 2/CU => ALL resident, single round (no tail). 8 waves/block
// (2x4 wave-grid) => 4 waves/SIMD of TLP to hide the per-iter A-latency. Per-wave K-step work
// unchanged vs R11 (MI=4, 32 MFMA). LDS: sA 32KB | sB0 16KB | sB1 16KB (66KB incl. epilogue).
__global__ __launch_bounds__(512, 2)
void qkv_gemm_kernel(const float* __restrict__ Xq, const float* __restrict__ Xk,
                     const float* __restrict__ Xv,
                     const unsigned short* __restrict__ Wq, const unsigned short* __restrict__ Wk,
                     const unsigned short* __restrict__ Wv,
                     const float* __restrict__ bq, const float* __restrict__ bk,
                     const float* __restrict__ bv,
                     unsigned short* __restrict__ Qp, unsigned short* __restrict__ Kp,
                     unsigned short* __restrict__ Vtp)
{
  constexpr int MI = 4;            // per-wave m-frags (wave tile 64x64)
  constexpr int NK = DMODEL/64;    // 16
  __shared__ __align__(16) unsigned short smem[33792];   // 67.5KB: GEMM 64KB; transpose 128x264

  const int m0   = blockIdx.x * 256;
  const int nabs = blockIdx.y * 128;
  const int wsel = nabs >> 10;        // 0=Q 1=K 2=V
  const int n0   = nabs & 1023;
  const float* A          = wsel==0 ? Xq : wsel==1 ? Xk : Xv;
  const unsigned short* W = wsel==0 ? Wq : wsel==1 ? Wk : Wv;
  const float* bias       = wsel==0 ? bq : wsel==1 ? bk : bv;

  const int t = threadIdx.x, lane = t & 63, wvx = t >> 6;
  const int wm = wvx >> 1, wn = wvx & 1;                  // wm in [0,4), wn in [0,2)
  const int lr = lane & 15, lk = lane >> 4;

  // A-staging decode: 4 chunks x 512 threads x 16B = 32KB (rows [0,256))
  int aRow[4], aCol[4], aO[4];
  #pragma unroll
  for (int g = 0; g < 4; ++g) {
    const int o  = g*8192 + t*16;
    const int so = o ^ (((o >> 7) & 7) << 4);
    aO[g] = o; aRow[g] = so >> 7; aCol[g] = (so & 127) >> 1;
  }
  // B-staging decode: 2 chunks x 512 x 16B = 16KB (rows [0,128))
  int bRow[2], bCol[2], bO[2];
  #pragma unroll
  for (int g = 0; g < 2; ++g) {
    const int o  = g*8192 + t*16;
    const int so = o ^ (((o >> 7) & 7) << 4);
    bO[g] = o; bRow[g] = so >> 7; bCol[g] = (so & 127) >> 1;
  }

  f32x4 acc[MI][4];
  #pragma unroll
  for (int mi = 0; mi < MI; ++mi)
    #pragma unroll
    for (int ni = 0; ni < 4; ++ni)
      acc[mi][ni] = {0.f, 0.f, 0.f, 0.f};

  float4 aLo[4], aHi[4];
  // prologue: A(0) regs + B(0) into sB0 (byte 32768)
  #pragma unroll
  for (int g = 0; g < 4; ++g) {
    const float* s = A + (size_t)(m0 + aRow[g])*DMODEL + aCol[g];
    aLo[g] = *(const float4*)(s);
    aHi[g] = *(const float4*)(s + 4);
  }
  #pragma unroll
  for (int g = 0; g < 2; ++g)
    async16((char*)smem + 32768 + bO[g], W + (size_t)(n0 + bRow[g])*DMODEL + bCol[g]);

  for (int kt = 0; kt < NK; ++kt) {
    // (a) A(kt) regs + B(kt) LDS landed
    asm volatile("s_waitcnt vmcnt(0)" ::: "memory");
    // (b) convert + write A(kt)
    #pragma unroll
    for (int g = 0; g < 4; ++g) {
      union { uint4 v; unsigned u[4]; } r;
      r.u[0] = cvt_pk_bf16(aLo[g].x, aLo[g].y);
      r.u[1] = cvt_pk_bf16(aLo[g].z, aLo[g].w);
      r.u[2] = cvt_pk_bf16(aHi[g].x, aHi[g].y);
      r.u[3] = cvt_pk_bf16(aHi[g].z, aHi[g].w);
      *(uint4*)((char*)smem + aO[g]) = r.v;
    }
    asm volatile("s_waitcnt lgkmcnt(0)" ::: "memory");
    // (c) A(kt)+B(kt) visible
    __builtin_amdgcn_s_barrier();
    // (d) issue next tile's loads
    if (kt + 1 < NK) {
      #pragma unroll
      for (int g = 0; g < 4; ++g) {
        const float* s = A + (size_t)(m0 + aRow[g])*DMODEL + (kt + 1)*64 + aCol[g];
        aLo[g] = *(const float4*)(s);
        aHi[g] = *(const float4*)(s + 4);
      }
      const int nb = 32768 + ((kt + 1) & 1)*16384;   // bytes: sB0 @32K, sB1 @48K
      #pragma unroll
      for (int g = 0; g < 2; ++g)
        async16((char*)smem + nb + bO[g], W + (size_t)(n0 + bRow[g])*DMODEL + (kt + 1)*64 + bCol[g]);
    }
    // (e) compute(kt)
    const unsigned short* sBu = smem + 16384 + (kt & 1)*8192;   // ushort offsets
    #pragma unroll
    for (int ks = 0; ks < 2; ++ks) {
      short8 af[MI], bf[4];
      #pragma unroll
      for (int mi = 0; mi < MI; ++mi) {
        const int row = wm*64 + mi*16 + lr;                     // [0,256)
        const int sl  = (ks*4 + lk) ^ (row & 7);
        af[mi] = *(const short8*)(smem + row*64 + sl*8);
      }
      #pragma unroll
      for (int ni = 0; ni < 4; ++ni) {
        const int row = wn*64 + ni*16 + lr;                     // [0,128)
        const int sl  = (ks*4 + lk) ^ (row & 7);
        bf[ni] = *(const short8*)(sBu + row*64 + sl*8);
      }
      #pragma unroll
      for (int mi = 0; mi < MI; ++mi)
        #pragma unroll
        for (int ni = 0; ni < 4; ++ni)
          acc[mi][ni] = __builtin_amdgcn_mfma_f32_16x16x32_bf16(af[mi], bf[ni], acc[mi][ni], 0, 0, 0);
    }
    // (f) reads done before next overwrite
    __builtin_amdgcn_s_barrier();
  }
  __syncthreads();

  if (wsel == 2) {
    // V: transpose through LDS (stride 264 us, 16B-aligned rows), coalesced 16B stores
    #pragma unroll
    for (int ni = 0; ni < 4; ++ni) {
      const float badd = bias[n0 + wn*64 + ni*16 + lr];
      #pragma unroll
      for (int mi = 0; mi < MI; ++mi)
        #pragma unroll
        for (int r = 0; r < 4; ++r) {
          const int ml = wm*64 + mi*16 + lk*4 + r;              // [0,256)
          smem[(wn*64 + ni*16 + lr)*264 + ml] = f32_to_bf16_rn(acc[mi][ni][r] + badd);
        }
    }
    __syncthreads();
    const int bb = m0 >> 11, s0 = m0 & 2047;
    const int jr = (t & 31)*8, nr = t >> 5;                     // 32 s-groups x 16 n-rows
    #pragma unroll
    for (int pass = 0; pass < 8; ++pass) {
      const int n  = pass*16 + nr;
      const int nn = n0 + n, hh = nn >> 6, d = nn & 63;
      const short8 v = *(const short8*)(smem + n*264 + jr);
      *(short8*)(Vtp + (((size_t)bb*NHEADS + hh)*64 + d)*SEQ + s0 + jr) = v;
    }
  } else {
    unsigned short* dst = wsel==0 ? Qp : Kp;
    // fold 1/sqrt(d_k) AND log2(e) into Q so attention softmax uses raw exp2
    const float qscale = (wsel == 0) ? 0.125f * 1.4426950408889634f : 1.0f;
    #pragma unroll
    for (int ni = 0; ni < 4; ++ni) {
      const int nn = n0 + wn*64 + ni*16 + lr;
      const float badd = bias[nn];
      const int hh = nn >> 6, d = nn & 63;
      #pragma unroll
      for (int mi = 0; mi < MI; ++mi) {
        #pragma unroll
        for (int r = 0; r < 4; ++r) {
          const int m = m0 + wm*64 + mi*16 + lk*4 + r;
          const int bb = m >> 11, s = m & 2047;
          const float v = (acc[mi][ni][r] + badd) * qscale;
          dst[(((size_t)bb*NHEADS + hh)*SEQ + s)*64 + d] = f32_to_bf16_rn(v);
        }
      }
    }
  }
}

// ---------------- flash attention (R10 exact: known-good 45.5us) ----------------
__global__ __launch_bounds__(256, 2)
void attn_kernel(const unsigned short* __restrict__ Qp, const unsigned short* __restrict__ Kp,
                 const unsigned short* __restrict__ Vtp, unsigned short* __restrict__ Op)
{
  __shared__ __align__(16) unsigned short sm[16384];  // 32KB: 2 bufs x (K 8KB + V 8KB)
  constexpr int NT = SEQ/64;   // 32 tiles

  const int t = threadIdx.x, lane = t & 63, w = t >> 6;
  const int lq = lane & 31, hi = lane >> 5;
  const int f   = blockIdx.x;
  const int wid = (f & 7)*64 + (f >> 3);               // XCD swizzle, 512 % 8 == 0
  const int qt = wid & 15, h = (wid >> 4) & 15, b = wid >> 8;

  const size_t bh = (size_t)b*NHEADS + h;
  const unsigned short* Qh = Qp  + bh*SEQ*64;
  const unsigned short* Kh = Kp  + bh*SEQ*64;
  const unsigned short* Vh = Vtp + bh*64*SEQ;
  const int q0 = qt*128 + w*32;

  short8 qf[4];
  #pragma unroll
  for (int ks = 0; ks < 4; ++ks)
    qf[ks] = *(const short8*)(Qh + (size_t)(q0 + lq)*64 + ks*16 + hi*8);

  f32x16 z16;
  #pragma unroll
  for (int r = 0; r < 16; ++r) z16[r] = 0.f;

  const unsigned short* srcp0;
  size_t sstride;
  if (w < 2) { srcp0 = Kh + (size_t)(w*32 + lq)*64 + hi*8;       sstride = 64*64; }
  else       { srcp0 = Vh + (size_t)((w-2)*32 + lq)*2048 + hi*8; sstride = 64;    }

  #pragma unroll
  for (int i = 0; i < 4; ++i)
    async16((char*)sm + w*4096 + i*1024, srcp0 + i*16);

  f32x16 o[2];
  float lsa[4] = {0.f, 0.f, 0.f, 0.f};
  #pragma unroll
  for (int d = 0; d < 2; ++d)
    #pragma unroll
    for (int r = 0; r < 16; ++r) o[d][r] = 0.f;

  for (int kt = 0; kt < NT; ++kt) {
    {
      const unsigned short* sp = srcp0 + (size_t)((kt + 1) & (NT - 1))*sstride;
      const int nb = ((kt + 1) & 1) * 16384;
      #pragma unroll
      for (int i = 0; i < 4; ++i)
        async16((char*)sm + nb + w*4096 + i*1024, sp + i*16);
    }
    asm volatile("s_waitcnt vmcnt(4)" ::: "memory");
    __builtin_amdgcn_s_barrier();

    const unsigned short* base  = sm + (kt & 1)*8192;
    const unsigned short* vbase = base + 4096;

    f32x16 st[2];
    #pragma unroll
    for (int sub = 0; sub < 2; ++sub) {
      #pragma unroll
      for (int ks = 0; ks < 4; ++ks) {
        const short8 kf = *(const short8*)(base + (sub*4 + ks)*512 + lane*8);
        if (ks == 0)
          st[sub] = __builtin_amdgcn_mfma_f32_32x32x16_bf16(kf, qf[0], z16, 0, 0, 0);
        else
          st[sub] = __builtin_amdgcn_mfma_f32_32x32x16_bf16(kf, qf[ks], st[sub], 0, 0, 0);
      }
    }

    unsigned pw[2][8];
    #pragma unroll
    for (int sub = 0; sub < 2; ++sub) {
      #pragma unroll
      for (int r = 0; r < 16; ++r) {
        const float p = __builtin_amdgcn_exp2f(st[sub][r]);
        st[sub][r] = p;
        lsa[r & 3] += p;
      }
      unsigned x0 = cvt_pk_bf16(st[sub][0],  st[sub][1]);
      unsigned x1 = cvt_pk_bf16(st[sub][2],  st[sub][3]);
      unsigned y0 = cvt_pk_bf16(st[sub][4],  st[sub][5]);
      unsigned y1 = cvt_pk_bf16(st[sub][6],  st[sub][7]);
      permlane32_swap(x0, y0);
      permlane32_swap(x1, y1);
      pw[sub][0] = x0; pw[sub][1] = x1; pw[sub][2] = y0; pw[sub][3] = y1;
      unsigned z0 = cvt_pk_bf16(st[sub][8],  st[sub][9]);
      unsigned z1 = cvt_pk_bf16(st[sub][10], st[sub][11]);
      unsigned w0 = cvt_pk_bf16(st[sub][12], st[sub][13]);
      unsigned w1 = cvt_pk_bf16(st[sub][14], st[sub][15]);
      permlane32_swap(z0, w0);
      permlane32_swap(z1, w1);
      pw[sub][4] = z0; pw[sub][5] = z1; pw[sub][6] = w0; pw[sub][7] = w1;
    }

    #pragma unroll
    for (int sub = 0; sub < 2; ++sub) {
      const short8 v00 = *(const short8*)(vbase + (0*4 + 2*sub    )*512 + lane*8);
      const short8 v01 = *(const short8*)(vbase + (0*4 + 2*sub + 1)*512 + lane*8);
      const short8 v10 = *(const short8*)(vbase + (1*4 + 2*sub    )*512 + lane*8);
      const short8 v11 = *(const short8*)(vbase + (1*4 + 2*sub + 1)*512 + lane*8);
      union { unsigned u[4]; short8 s; } pA, pB;
      pA.u[0] = pw[sub][0]; pA.u[1] = pw[sub][1]; pA.u[2] = pw[sub][2]; pA.u[3] = pw[sub][3];
      pB.u[0] = pw[sub][4]; pB.u[1] = pw[sub][5]; pB.u[2] = pw[sub][6]; pB.u[3] = pw[sub][7];
      o[0] = __builtin_amdgcn_mfma_f32_32x32x16_bf16(v00, pA.s, o[0], 0, 0, 0);
      o[1] = __builtin_amdgcn_mfma_f32_32x32x16_bf16(v10, pA.s, o[1], 0, 0, 0);
      o[0] = __builtin_amdgcn_mfma_f32_32x32x16_bf16(v01, pB.s, o[0], 0, 0, 0);
      o[1] = __builtin_amdgcn_mfma_f32_32x32x16_bf16(v11, pB.s, o[1], 0, 0, 0);
    }
    asm volatile("" ::: "memory");
    __builtin_amdgcn_s_barrier();
  }

  float lsum = (lsa[0] + lsa[1]) + (lsa[2] + lsa[3]);
  lsum += __shfl_xor(lsum, 32);
  const float inv = __builtin_amdgcn_rcpf(lsum);
  unsigned short* orow = Op + ((size_t)b*SEQ + q0 + lq)*DMODEL + h*64;
  #pragma unroll
  for (int dblk = 0; dblk < 2; ++dblk)
    #pragma unroll
    for (int g = 0; g < 4; ++g) {
      union { unsigned short us[4]; uint2 v; } pk;
      #pragma unroll
      for (int r = 0; r < 4; ++r) pk.us[r] = f32_to_bf16_rn(o[dblk][g*4 + r] * inv);
      *(uint2*)(orow + dblk*32 + g*8 + hi*4) = pk.v;
    }
}

// ---------------- output projection: grid (64, 8), BM=64 (R11 exact) ----------------
__global__ __launch_bounds__(256, 2)
void oproj_gemm_kernel(const unsigned short* __restrict__ Oin, const unsigned short* __restrict__ Wo,
                       const float* __restrict__ bo, float* __restrict__ out)
{
  constexpr int BM = 64;
  constexpr int MI = BM/32;
  __shared__ __align__(16) unsigned short sA[BM*64];
  __shared__ __align__(16) unsigned short sB[128*64];
  const int m0 = blockIdx.x * BM;
  const int n0 = blockIdx.y * 128;

  f32x4 acc[MI][4];
  #pragma unroll
  for (int mi = 0; mi < MI; ++mi)
    #pragma unroll
    for (int ni = 0; ni < 4; ++ni)
      acc[mi][ni] = {0.f,0.f,0.f,0.f};

  gemm_core<BM>(Oin, Wo, sA, sB, m0, n0, acc);

  const int t = threadIdx.x, lane = t & 63, wvx = t >> 6;
  const int wm = wvx >> 1, wn = wvx & 1;
  const int lr = lane & 15, lk = lane >> 4;

  #pragma unroll
  for (int ni = 0; ni < 4; ++ni) {
    const int nn = n0 + wn*64 + ni*16 + lr;
    const float badd = bo[nn];
    #pragma unroll
    for (int mi = 0; mi < MI; ++mi)
      #pragma unroll
      for (int r = 0; r < 4; ++r) {
        const int m = m0 + wm*(BM/2) + mi*16 + lk*4 + r;
        out[(size_t)m*DMODEL + nn] = acc[mi][ni][r] + badd;
      }
  }
}

// ---------------- host launch ----------------
extern "C" void kernel_launch(void* const* d_in, const int* in_sizes, int n_in,
                              void* d_out, int out_size, void* d_ws, size_t ws_size,
                              hipStream_t stream) {
  const float* query = (const float*)d_in[0];
  const float* key   = (const float*)d_in[1];
  const float* value = (const float*)d_in[2];
  const float* Wq    = (const float*)d_in[3];
  const float* bq    = (const float*)d_in[4];
  const float* Wk    = (const float*)d_in[5];
  const float* bk    = (const float*)d_in[6];
  const float* Wv    = (const float*)d_in[7];
  const float* bv    = (const float*)d_in[8];
  const float* Wo    = (const float*)d_in[9];
  const float* bo    = (const float*)d_in[10];

  const size_t NX = (size_t)MTOT*DMODEL;    // 2^22
  const size_t NW = (size_t)DMODEL*DMODEL;  // 2^20
  unsigned short* w   = (unsigned short*)d_ws;
  unsigned short* Wqp = w + 3*NX;           // X slots unused; keep layout
  unsigned short* Wkp = Wqp + NW;
  unsigned short* Wvp = Wkp + NW;
  unsigned short* Wop = Wvp + NW;
  unsigned short* Qp  = Wop + NW;
  unsigned short* Kp  = Qp  + NX;
  unsigned short* Vtp = Kp  + NX;
  unsigned short* Opb = Vtp + NX;

  cvt_w_kernel<<<dim3(512, 4), 256, 0, stream>>>(Wq, Wk, Wv, Wo, Wqp);
  qkv_gemm_kernel<<<dim3(16, 24), 512, 0, stream>>>(
      query, key, value, Wqp, Wkp, Wvp, bq, bk, bv, Qp, Kp, Vtp);
  attn_kernel<<<dim3(512), 256, 0, stream>>>(Qp, Kp, Vtp, Opb);
  oproj_gemm_kernel<<<dim3(64, 8), 256, 0, stream>>>(Opb, Wop, bo, (float*)d_out);
}

// Round 21
// 104.896 us; speedup vs baseline: 1.1315x; 1.1315x over previous
//
#include <hip/hip_runtime.h>

#define NHEADS 16
#define SEQ    2048
#define BATCH  2
#define DMODEL 1024
#define MTOT   4096   // BATCH*SEQ

typedef __attribute__((ext_vector_type(8)))  short short8;
typedef __attribute__((ext_vector_type(4)))  float f32x4;
typedef __attribute__((ext_vector_type(16))) float f32x16;

__device__ __forceinline__ unsigned short f32_to_bf16_rn(float x) {
  unsigned int u = __float_as_uint(x);
  u += 0x7fffu + ((u >> 16) & 1u);   // RNE
  return (unsigned short)(u >> 16);
}

__device__ __forceinline__ unsigned cvt_pk_bf16(float lo, float hi_) {
  unsigned r;
  asm("v_cvt_pk_bf16_f32 %0, %1, %2" : "=v"(r) : "v"(lo), "v"(hi_));
  return r;
}

// v_permlane32_swap_b32: after: a = {a.lo, b.lo}, b = {a.hi, b.hi}
__device__ __forceinline__ void permlane32_swap(unsigned &a, unsigned &b) {
  asm("v_permlane32_swap_b32 %0, %1" : "+v"(a), "+v"(b));
}

__device__ __forceinline__ void async16(void* lds, const void* g) {
  __builtin_amdgcn_global_load_lds((const __attribute__((address_space(1))) unsigned int*)g,
                                   (__attribute__((address_space(3))) unsigned int*)lds, 16, 0, 0);
}

// ---------------- fp32 -> bf16 conversion prepass: WEIGHTS ONLY (X fused into qkv) ----------
__global__ void cvt_w_kernel(const float* __restrict__ w0, const float* __restrict__ w1,
                             const float* __restrict__ w2, const float* __restrict__ w3,
                             unsigned short* __restrict__ obase)
{
  const int which = blockIdx.y;
  const float* src = which==0 ? w0 : which==1 ? w1 : which==2 ? w2 : w3;
  const int i = (blockIdx.x*256 + threadIdx.x)*8;
  const float4 v0 = *(const float4*)(src + i);
  const float4 v1 = *(const float4*)(src + i + 4);
  union { unsigned short u[8]; uint4 v; } r;
  r.u[0] = f32_to_bf16_rn(v0.x); r.u[1] = f32_to_bf16_rn(v0.y);
  r.u[2] = f32_to_bf16_rn(v0.z); r.u[3] = f32_to_bf16_rn(v0.w);
  r.u[4] = f32_to_bf16_rn(v1.x); r.u[5] = f32_to_bf16_rn(v1.y);
  r.u[6] = f32_to_bf16_rn(v1.z); r.u[7] = f32_to_bf16_rn(v1.w);
  *(uint4*)(obase + (size_t)which*1048576 + i) = r.v;
}

// ---------------- shared NT-GEMM core (bf16 A) — used by oproj ----------------
template<int BM>
__device__ __forceinline__ void gemm_core(const unsigned short* __restrict__ A,
                                          const unsigned short* __restrict__ W,
                                          unsigned short* sA, unsigned short* sB,
                                          int m0, int n0, f32x4 (&acc)[BM/32][4])
{
  constexpr int MI = BM/32;
  const int t = threadIdx.x;
  const int lane = t & 63;
  const int wv = t >> 6;
  const int wm = wv >> 1, wn = wv & 1;
  const int lr = lane & 15, lk = lane >> 4;

  for (int kt = 0; kt < DMODEL/64; ++kt) {
    #pragma unroll
    for (int g = 0; g < MI; ++g) {
      const int o  = g*4096 + t*16;
      const int so = o ^ (((o >> 7) & 7) << 4);
      const int row = so >> 7, colE = (so & 127) >> 1;
      async16((char*)sA + o, A + (size_t)(m0 + row)*DMODEL + kt*64 + colE);
    }
    #pragma unroll
    for (int g = 0; g < 4; ++g) {
      const int o  = g*4096 + t*16;
      const int so = o ^ (((o >> 7) & 7) << 4);
      const int row = so >> 7, colE = (so & 127) >> 1;
      async16((char*)sB + o, W + (size_t)(n0 + row)*DMODEL + kt*64 + colE);
    }
    __syncthreads();
    #pragma unroll
    for (int ks = 0; ks < 2; ++ks) {
      short8 af[MI], bf[4];
      #pragma unroll
      for (int mi = 0; mi < MI; ++mi) {
        const int row = wm*(BM/2) + mi*16 + lr;
        const int sl  = (ks*4 + lk) ^ (row & 7);
        af[mi] = *(const short8*)(sA + row*64 + sl*8);
      }
      #pragma unroll
      for (int ni = 0; ni < 4; ++ni) {
        const int row = wn*64 + ni*16 + lr;
        const int sl  = (ks*4 + lk) ^ (row & 7);
        bf[ni] = *(const short8*)(sB + row*64 + sl*8);
      }
      #pragma unroll
      for (int mi = 0; mi < MI; ++mi)
        #pragma unroll
        for (int ni = 0; ni < 4; ++ni)
          acc[mi][ni] = __builtin_amdgcn_mfma_f32_16x16x32_bf16(af[mi], bf[ni], acc[mi][ni], 0, 0, 0);
    }
    __syncthreads();
  }
}

// ---------------- fused QKV projection, depth-1 pipeline (best-known config, 2x verified) ----
__global__ __launch_bounds__(256, 3)
void qkv_gemm_kernel(const float* __restrict__ Xq, const float* __restrict__ Xk,
                     const float* __restrict__ Xv,
                     const unsigned short* __restrict__ Wq, const unsigned short* __restrict__ Wk,
                     const unsigned short* __restrict__ Wv,
                     const float* __restrict__ bq, const float* __restrict__ bk,
                     const float* __restrict__ bv,
                     unsigned short* __restrict__ Qp, unsigned short* __restrict__ Kp,
                     unsigned short* __restrict__ Vtp)
{
  constexpr int MI = 4;            // BM = 128
  constexpr int NK = DMODEL/64;    // 16
  __shared__ __align__(16) unsigned short smem[24576];   // sA 16KB | sB0 16KB | sB1 16KB
  unsigned short* sA = smem;

  const int m0   = blockIdx.x * 128;
  const int nabs = blockIdx.y * 128;
  const int wsel = nabs >> 10;        // 0=Q 1=K 2=V
  const int n0   = nabs & 1023;
  const float* A          = wsel==0 ? Xq : wsel==1 ? Xk : Xv;
  const unsigned short* W = wsel==0 ? Wq : wsel==1 ? Wk : Wv;
  const float* bias       = wsel==0 ? bq : wsel==1 ? bk : bv;

  const int t = threadIdx.x, lane = t & 63, wvx = t >> 6;
  const int wm = wvx >> 1, wn = wvx & 1;
  const int lr = lane & 15, lk = lane >> 4;

  int aRow[MI], aCol[MI], aO[MI];
  #pragma unroll
  for (int g = 0; g < MI; ++g) {
    const int o  = g*4096 + t*16;
    const int so = o ^ (((o >> 7) & 7) << 4);
    aO[g] = o; aRow[g] = so >> 7; aCol[g] = (so & 127) >> 1;
  }

  f32x4 acc[MI][4];
  #pragma unroll
  for (int mi = 0; mi < MI; ++mi)
    #pragma unroll
    for (int ni = 0; ni < 4; ++ni)
      acc[mi][ni] = {0.f, 0.f, 0.f, 0.f};

  float4 aLo[MI], aHi[MI];
  #pragma unroll
  for (int g = 0; g < MI; ++g) {
    const float* s = A + (size_t)(m0 + aRow[g])*DMODEL + aCol[g];
    aLo[g] = *(const float4*)(s);
    aHi[g] = *(const float4*)(s + 4);
  }
  #pragma unroll
  for (int g = 0; g < 4; ++g)
    async16((char*)smem + 16384 + aO[g], W + (size_t)(n0 + aRow[g])*DMODEL + aCol[g]);

  for (int kt = 0; kt < NK; ++kt) {
    asm volatile("s_waitcnt vmcnt(0)" ::: "memory");
    #pragma unroll
    for (int g = 0; g < MI; ++g) {
      union { uint4 v; unsigned u[4]; } r;
      r.u[0] = cvt_pk_bf16(aLo[g].x, aLo[g].y);
      r.u[1] = cvt_pk_bf16(aLo[g].z, aLo[g].w);
      r.u[2] = cvt_pk_bf16(aHi[g].x, aHi[g].y);
      r.u[3] = cvt_pk_bf16(aHi[g].z, aHi[g].w);
      *(uint4*)((char*)sA + aO[g]) = r.v;
    }
    asm volatile("s_waitcnt lgkmcnt(0)" ::: "memory");
    __builtin_amdgcn_s_barrier();
    if (kt + 1 < NK) {
      #pragma unroll
      for (int g = 0; g < MI; ++g) {
        const float* s = A + (size_t)(m0 + aRow[g])*DMODEL + (kt + 1)*64 + aCol[g];
        aLo[g] = *(const float4*)(s);
        aHi[g] = *(const float4*)(s + 4);
      }
      const int nb = 16384 + ((kt + 1) & 1)*8192*2;
      #pragma unroll
      for (int g = 0; g < 4; ++g)
        async16((char*)smem + nb + aO[g], W + (size_t)(n0 + aRow[g])*DMODEL + (kt + 1)*64 + aCol[g]);
    }
    const unsigned short* sB = smem + 8192 + (kt & 1)*8192;
    #pragma unroll
    for (int ks = 0; ks < 2; ++ks) {
      short8 af[MI], bf[4];
      #pragma unroll
      for (int mi = 0; mi < MI; ++mi) {
        const int row = wm*64 + mi*16 + lr;
        const int sl  = (ks*4 + lk) ^ (row & 7);
        af[mi] = *(const short8*)(sA + row*64 + sl*8);
      }
      #pragma unroll
      for (int ni = 0; ni < 4; ++ni) {
        const int row = wn*64 + ni*16 + lr;
        const int sl  = (ks*4 + lk) ^ (row & 7);
        bf[ni] = *(const short8*)(sB + row*64 + sl*8);
      }
      #pragma unroll
      for (int mi = 0; mi < MI; ++mi)
        #pragma unroll
        for (int ni = 0; ni < 4; ++ni)
          acc[mi][ni] = __builtin_amdgcn_mfma_f32_16x16x32_bf16(af[mi], bf[ni], acc[mi][ni], 0, 0, 0);
    }
    __builtin_amdgcn_s_barrier();
  }
  __syncthreads();

  if (wsel == 2) {
    // V: transpose through LDS (pad stride 132), then coalesced 16B row stores to Vt[b,h,d,s]
    #pragma unroll
    for (int ni = 0; ni < 4; ++ni) {
      const float badd = bias[n0 + wn*64 + ni*16 + lr];
      #pragma unroll
      for (int mi = 0; mi < MI; ++mi)
        #pragma unroll
        for (int r = 0; r < 4; ++r) {
          const int ml = wm*64 + mi*16 + lk*4 + r;
          smem[(wn*64 + ni*16 + lr)*132 + ml] = f32_to_bf16_rn(acc[mi][ni][r] + badd);
        }
    }
    __syncthreads();
    const int bb = m0 >> 11, s0 = m0 & 2047;
    const int jr = (t & 15)*8, nr = t >> 4;
    #pragma unroll
    for (int pass = 0; pass < 8; ++pass) {
      const int n  = pass*16 + nr;
      const int nn = n0 + n, hh = nn >> 6, d = nn & 63;
      const short8 v = *(const short8*)(smem + n*132 + jr);
      *(short8*)(Vtp + (((size_t)bb*NHEADS + hh)*64 + d)*SEQ + s0 + jr) = v;
    }
  } else {
    unsigned short* dst = wsel==0 ? Qp : Kp;
    // fold 1/sqrt(d_k) AND log2(e) into Q so attention softmax uses raw exp2
    const float qscale = (wsel == 0) ? 0.125f * 1.4426950408889634f : 1.0f;
    #pragma unroll
    for (int ni = 0; ni < 4; ++ni) {
      const int nn = n0 + wn*64 + ni*16 + lr;
      const float badd = bias[nn];
      const int hh = nn >> 6, d = nn & 63;
      #pragma unroll
      for (int mi = 0; mi < MI; ++mi) {
        #pragma unroll
        for (int r = 0; r < 4; ++r) {
          const int m = m0 + wm*64 + mi*16 + lk*4 + r;
          const int bb = m >> 11, s = m & 2047;
          const float v = (acc[mi][ni][r] + badd) * qscale;
          dst[(((size_t)bb*NHEADS + hh)*SEQ + s)*64 + d] = f32_to_bf16_rn(v);
        }
      }
    }
  }
}

// ---------------- flash attention (R10 exact: known-good 45.5us, 4x verified) ----------------
__global__ __launch_bounds__(256, 2)
void attn_kernel(const unsigned short* __restrict__ Qp, const unsigned short* __restrict__ Kp,
                 const unsigned short* __restrict__ Vtp, unsigned short* __restrict__ Op)
{
  __shared__ __align__(16) unsigned short sm[16384];  // 32KB: 2 bufs x (K 8KB + V 8KB)
  constexpr int NT = SEQ/64;   // 32 tiles

  const int t = threadIdx.x, lane = t & 63, w = t >> 6;
  const int lq = lane & 31, hi = lane >> 5;
  const int f   = blockIdx.x;
  const int wid = (f & 7)*64 + (f >> 3);               // XCD swizzle, 512 % 8 == 0
  const int qt = wid & 15, h = (wid >> 4) & 15, b = wid >> 8;

  const size_t bh = (size_t)b*NHEADS + h;
  const unsigned short* Qh = Qp  + bh*SEQ*64;
  const unsigned short* Kh = Kp  + bh*SEQ*64;
  const unsigned short* Vh = Vtp + bh*64*SEQ;
  const int q0 = qt*128 + w*32;

  short8 qf[4];
  #pragma unroll
  for (int ks = 0; ks < 4; ++ks)
    qf[ks] = *(const short8*)(Qh + (size_t)(q0 + lq)*64 + ks*16 + hi*8);

  f32x16 z16;
  #pragma unroll
  for (int r = 0; r < 16; ++r) z16[r] = 0.f;

  const unsigned short* srcp0;
  size_t sstride;
  if (w < 2) { srcp0 = Kh + (size_t)(w*32 + lq)*64 + hi*8;       sstride = 64*64; }
  else       { srcp0 = Vh + (size_t)((w-2)*32 + lq)*2048 + hi*8; sstride = 64;    }

  #pragma unroll
  for (int i = 0; i < 4; ++i)
    async16((char*)sm + w*4096 + i*1024, srcp0 + i*16);

  f32x16 o[2];
  float lsa[4] = {0.f, 0.f, 0.f, 0.f};
  #pragma unroll
  for (int d = 0; d < 2; ++d)
    #pragma unroll
    for (int r = 0; r < 16; ++r) o[d][r] = 0.f;

  for (int kt = 0; kt < NT; ++kt) {
    {
      const unsigned short* sp = srcp0 + (size_t)((kt + 1) & (NT - 1))*sstride;
      const int nb = ((kt + 1) & 1) * 16384;
      #pragma unroll
      for (int i = 0; i < 4; ++i)
        async16((char*)sm + nb + w*4096 + i*1024, sp + i*16);
    }
    asm volatile("s_waitcnt vmcnt(4)" ::: "memory");
    __builtin_amdgcn_s_barrier();

    const unsigned short* base  = sm + (kt & 1)*8192;
    const unsigned short* vbase = base + 4096;

    f32x16 st[2];
    #pragma unroll
    for (int sub = 0; sub < 2; ++sub) {
      #pragma unroll
      for (int ks = 0; ks < 4; ++ks) {
        const short8 kf = *(const short8*)(base + (sub*4 + ks)*512 + lane*8);
        if (ks == 0)
          st[sub] = __builtin_amdgcn_mfma_f32_32x32x16_bf16(kf, qf[0], z16, 0, 0, 0);
        else
          st[sub] = __builtin_amdgcn_mfma_f32_32x32x16_bf16(kf, qf[ks], st[sub], 0, 0, 0);
      }
    }

    unsigned pw[2][8];
    #pragma unroll
    for (int sub = 0; sub < 2; ++sub) {
      #pragma unroll
      for (int r = 0; r < 16; ++r) {
        const float p = __builtin_amdgcn_exp2f(st[sub][r]);
        st[sub][r] = p;
        lsa[r & 3] += p;
      }
      unsigned x0 = cvt_pk_bf16(st[sub][0],  st[sub][1]);
      unsigned x1 = cvt_pk_bf16(st[sub][2],  st[sub][3]);
      unsigned y0 = cvt_pk_bf16(st[sub][4],  st[sub][5]);
      unsigned y1 = cvt_pk_bf16(st[sub][6],  st[sub][7]);
      permlane32_swap(x0, y0);
      permlane32_swap(x1, y1);
      pw[sub][0] = x0; pw[sub][1] = x1; pw[sub][2] = y0; pw[sub][3] = y1;
      unsigned z0 = cvt_pk_bf16(st[sub][8],  st[sub][9]);
      unsigned z1 = cvt_pk_bf16(st[sub][10], st[sub][11]);
      unsigned w0 = cvt_pk_bf16(st[sub][12], st[sub][13]);
      unsigned w1 = cvt_pk_bf16(st[sub][14], st[sub][15]);
      permlane32_swap(z0, w0);
      permlane32_swap(z1, w1);
      pw[sub][4] = z0; pw[sub][5] = z1; pw[sub][6] = w0; pw[sub][7] = w1;
    }

    #pragma unroll
    for (int sub = 0; sub < 2; ++sub) {
      const short8 v00 = *(const short8*)(vbase + (0*4 + 2*sub    )*512 + lane*8);
      const short8 v01 = *(const short8*)(vbase + (0*4 + 2*sub + 1)*512 + lane*8);
      const short8 v10 = *(const short8*)(vbase + (1*4 + 2*sub    )*512 + lane*8);
      const short8 v11 = *(const short8*)(vbase + (1*4 + 2*sub + 1)*512 + lane*8);
      union { unsigned u[4]; short8 s; } pA, pB;
      pA.u[0] = pw[sub][0]; pA.u[1] = pw[sub][1]; pA.u[2] = pw[sub][2]; pA.u[3] = pw[sub][3];
      pB.u[0] = pw[sub][4]; pB.u[1] = pw[sub][5]; pB.u[2] = pw[sub][6]; pB.u[3] = pw[sub][7];
      o[0] = __builtin_amdgcn_mfma_f32_32x32x16_bf16(v00, pA.s, o[0], 0, 0, 0);
      o[1] = __builtin_amdgcn_mfma_f32_32x32x16_bf16(v10, pA.s, o[1], 0, 0, 0);
      o[0] = __builtin_amdgcn_mfma_f32_32x32x16_bf16(v01, pB.s, o[0], 0, 0, 0);
      o[1] = __builtin_amdgcn_mfma_f32_32x32x16_bf16(v11, pB.s, o[1], 0, 0, 0);
    }
    asm volatile("" ::: "memory");
    __builtin_amdgcn_s_barrier();
  }

  float lsum = (lsa[0] + lsa[1]) + (lsa[2] + lsa[3]);
  lsum += __shfl_xor(lsum, 32);
  const float inv = __builtin_amdgcn_rcpf(lsum);
  unsigned short* orow = Op + ((size_t)b*SEQ + q0 + lq)*DMODEL + h*64;
  #pragma unroll
  for (int dblk = 0; dblk < 2; ++dblk)
    #pragma unroll
    for (int g = 0; g < 4; ++g) {
      union { unsigned short us[4]; uint2 v; } pk;
      #pragma unroll
      for (int r = 0; r < 4; ++r) pk.us[r] = f32_to_bf16_rn(o[dblk][g*4 + r] * inv);
      *(uint2*)(orow + dblk*32 + g*8 + hi*4) = pk.v;
    }
}

// ---------------- output projection: grid (64, 8), BM=64 ----------------
__global__ __launch_bounds__(256, 2)
void oproj_gemm_kernel(const unsigned short* __restrict__ Oin, const unsigned short* __restrict__ Wo,
                       const float* __restrict__ bo, float* __restrict__ out)
{
  constexpr int BM = 64;
  constexpr int MI = BM/32;
  __shared__ __align__(16) unsigned short sA[BM*64];
  __shared__ __align__(16) unsigned short sB[128*64];
  const int m0 = blockIdx.x * BM;
  const int n0 = blockIdx.y * 128;

  f32x4 acc[MI][4];
  #pragma unroll
  for (int mi = 0; mi < MI; ++mi)
    #pragma unroll
    for (int ni = 0; ni < 4; ++ni)
      acc[mi][ni] = {0.f,0.f,0.f,0.f};

  gemm_core<BM>(Oin, Wo, sA, sB, m0, n0, acc);

  const int t = threadIdx.x, lane = t & 63, wvx = t >> 6;
  const int wm = wvx >> 1, wn = wvx & 1;
  const int lr = lane & 15, lk = lane >> 4;

  #pragma unroll
  for (int ni = 0; ni < 4; ++ni) {
    const int nn = n0 + wn*64 + ni*16 + lr;
    const float badd = bo[nn];
    #pragma unroll
    for (int mi = 0; mi < MI; ++mi)
      #pragma unroll
      for (int r = 0; r < 4; ++r) {
        const int m = m0 + wm*(BM/2) + mi*16 + lk*4 + r;
        out[(size_t)m*DMODEL + nn] = acc[mi][ni][r] + badd;
      }
  }
}

// ---------------- host launch ----------------
extern "C" void kernel_launch(void* const* d_in, const int* in_sizes, int n_in,
                              void* d_out, int out_size, void* d_ws, size_t ws_size,
                              hipStream_t stream) {
  const float* query = (const float*)d_in[0];
  const float* key   = (const float*)d_in[1];
  const float* value = (const float*)d_in[2];
  const float* Wq    = (const float*)d_in[3];
  const float* bq    = (const float*)d_in[4];
  const float* Wk    = (const float*)d_in[5];
  const float* bk    = (const float*)d_in[6];
  const float* Wv    = (const float*)d_in[7];
  const float* bv    = (const float*)d_in[8];
  const float* Wo    = (const float*)d_in[9];
  const float* bo    = (const float*)d_in[10];

  const size_t NX = (size_t)MTOT*DMODEL;    // 2^22
  const size_t NW = (size_t)DMODEL*DMODEL;  // 2^20
  unsigned short* w   = (unsigned short*)d_ws;
  unsigned short* Wqp = w + 3*NX;           // X slots unused; keep layout
  unsigned short* Wkp = Wqp + NW;
  unsigned short* Wvp = Wkp + NW;
  unsigned short* Wop = Wvp + NW;
  unsigned short* Qp  = Wop + NW;
  unsigned short* Kp  = Qp  + NX;
  unsigned short* Vtp = Kp  + NX;
  unsigned short* Opb = Vtp + NX;

  cvt_w_kernel<<<dim3(512, 4), 256, 0, stream>>>(Wq, Wk, Wv, Wo, Wqp);
  qkv_gemm_kernel<<<dim3(32, 24), 256, 0, stream>>>(
      query, key, value, Wqp, Wkp, Wvp, bq, bk, bv, Qp, Kp, Vtp);
  attn_kernel<<<dim3(512), 256, 0, stream>>>(Qp, Kp, Vtp, Opb);
  oproj_gemm_kernel<<<dim3(64, 8), 256, 0, stream>>>(Opb, Wop, bo, (float*)d_out);
}